// Round 2
// baseline (124.120 us; speedup 1.0000x reference)
//
#include <hip/hip_runtime.h>

#define NT 2000000
#define NE 20000
#define NTILES (NT / 64)   // 31250, exact

using bf16x8 = __attribute__((ext_vector_type(8))) __bf16;
using bf16x4 = __attribute__((ext_vector_type(4))) __bf16;
using f32x4  = __attribute__((ext_vector_type(4))) float;
using fvec4  = __attribute__((ext_vector_type(4))) float;

// hi/lo bf16 split of 8 consecutive f32 (for k2 precision)
__device__ __forceinline__ void load_bsplit(const float* __restrict__ p,
                                            bf16x8& hi, bf16x8& lo) {
    fvec4 a = *(const fvec4*)p;
    fvec4 b = *(const fvec4*)(p + 4);
#pragma unroll
    for (int e = 0; e < 4; e++) {
        float v  = a[e];
        __bf16 h = (__bf16)v;
        hi[e]    = h;
        lo[e]    = (__bf16)(v - (float)h);
        float v2  = b[e];
        __bf16 h2 = (__bf16)v2;
        hi[e + 4] = h2;
        lo[e + 4] = (__bf16)(v2 - (float)h2);
    }
}

// plain bf16 load of 8 consecutive f32
__device__ __forceinline__ bf16x8 load_bf8(const float* __restrict__ p) {
    fvec4 a = *(const fvec4*)p;
    fvec4 b = *(const fvec4*)(p + 4);
    bf16x8 r;
#pragma unroll
    for (int e = 0; e < 4; e++) {
        r[e]     = (__bf16)a[e];
        r[e + 4] = (__bf16)b[e];
    }
    return r;
}

// ---------------- K1: fused phi1 (2 layers) + jagged segment-sum ----------------
// No LDS. Reduce straight from MFMA C-layout; ballot-driven run handling.
__global__ __launch_bounds__(256, 3) void k1_phi1(
    const float* __restrict__ values, const int* __restrict__ seg,
    const float* __restrict__ w0, const float* __restrict__ b0,
    const float* __restrict__ w1, const float* __restrict__ b1,
    float* __restrict__ ev) {
    const int tid = threadIdx.x;
    const int w   = tid >> 6;
    const int l   = tid & 63;
    const int l15 = l & 15;
    const int l4  = l >> 4;

    // B fragments for W1 (bf16): lane holds col j=16jf+l15, k = 32kf+8*l4+e
    bf16x8 Bh[2][4];
#pragma unroll
    for (int kf = 0; kf < 2; kf++)
#pragma unroll
        for (int jf = 0; jf < 4; jf++)
            Bh[kf][jf] = load_bf8(w1 + (jf * 16 + l15) * 64 + kf * 32 + l4 * 8);

    // layer-1 weights (f32-exact) for this lane's 8 k's per kf
    float w0q[2][8], b0q[2][8];
#pragma unroll
    for (int kf = 0; kf < 2; kf++) {
        const int kb = kf * 32 + l4 * 8;
        fvec4 wa = *(const fvec4*)(w0 + kb);
        fvec4 wb = *(const fvec4*)(w0 + kb + 4);
        fvec4 ba = *(const fvec4*)(b0 + kb);
        fvec4 bb = *(const fvec4*)(b0 + kb + 4);
#pragma unroll
        for (int e = 0; e < 4; e++) {
            w0q[kf][e]     = wa[e];
            w0q[kf][e + 4] = wb[e];
            b0q[kf][e]     = ba[e];
            b0q[kf][e + 4] = bb[e];
        }
    }
    float biasj[4];
#pragma unroll
    for (int jf = 0; jf < 4; jf++) biasj[jf] = b1[jf * 16 + l15];

    for (int tile = blockIdx.x * 4 + w; tile < NTILES; tile += gridDim.x * 4) {
        const int base = tile * 64;
        const int s_l  = seg[base + l];                 // lane l: seg of particle l
        const int prev = __shfl_up(s_l, 1);
        const unsigned long long bmask = __ballot((l > 0) && (s_l != prev));

        float vp[4];
#pragma unroll
        for (int pf = 0; pf < 4; pf++) vp[pf] = values[base + pf * 16 + l15];

        f32x4 acc[4][4];
#pragma unroll
        for (int pf = 0; pf < 4; pf++)
#pragma unroll
            for (int jf = 0; jf < 4; jf++)
#pragma unroll
                for (int r = 0; r < 4; r++) acc[pf][jf][r] = biasj[jf];

#pragma unroll
        for (int kf = 0; kf < 2; kf++) {
            // h1 = relu(v*w0+b0) built directly in A-fragment layout (f32 math)
            bf16x8 A[4];
#pragma unroll
            for (int pf = 0; pf < 4; pf++) {
#pragma unroll
                for (int e = 0; e < 8; e++) {
                    float h = fmaxf(fmaf(vp[pf], w0q[kf][e], b0q[kf][e]), 0.f);
                    A[pf][e] = (__bf16)h;
                }
            }
#pragma unroll
            for (int pf = 0; pf < 4; pf++)
#pragma unroll
                for (int jf = 0; jf < 4; jf++)
                    acc[pf][jf] = __builtin_amdgcn_mfma_f32_16x16x32_bf16(
                        A[pf], Bh[kf][jf], acc[pf][jf], 0, 0, 0);
        }

        // relu in-register (h2), f32 precision kept for the reduce
#pragma unroll
        for (int pf = 0; pf < 4; pf++)
#pragma unroll
            for (int jf = 0; jf < 4; jf++)
#pragma unroll
                for (int r = 0; r < 4; r++)
                    acc[pf][jf][r] = fmaxf(acc[pf][jf][r], 0.f);

        if (bmask == 0ULL) {
            // uniform tile: full column sums, one atomic per lane (feature j==l)
            const int sid = __builtin_amdgcn_readlane(s_l, 0);
            float sj[4];
#pragma unroll
            for (int jf = 0; jf < 4; jf++) {
                f32x4 t = (acc[0][jf] + acc[1][jf]) + (acc[2][jf] + acc[3][jf]);
                float h = (t[0] + t[1]) + (t[2] + t[3]);
                h += __shfl_xor(h, 16);
                h += __shfl_xor(h, 32);
                sj[jf] = h;
            }
            float v = (l4 == 0) ? sj[0] : (l4 == 1) ? sj[1]
                    : (l4 == 2) ? sj[2] : sj[3];
            atomicAdd(ev + (size_t)sid * 64 + l, v);
        } else {
            // run loop: boundaries are wave-uniform scalars from the ballot mask
            unsigned long long m = bmask;
            int start = 0;
            int sid   = __builtin_amdgcn_readlane(s_l, 0);
            while (true) {
                const int end = m ? (int)__builtin_ctzll(m) : 64;
                float sj[4] = {0.f, 0.f, 0.f, 0.f};
#pragma unroll
                for (int pf = 0; pf < 4; pf++)
#pragma unroll
                    for (int r = 0; r < 4; r++) {
                        const int p  = pf * 16 + l4 * 4 + r;
                        const float pm = (p >= start && p < end) ? 1.f : 0.f;
#pragma unroll
                        for (int jf = 0; jf < 4; jf++)
                            sj[jf] = fmaf(acc[pf][jf][r], pm, sj[jf]);
                    }
#pragma unroll
                for (int jf = 0; jf < 4; jf++) {
                    sj[jf] += __shfl_xor(sj[jf], 16);
                    sj[jf] += __shfl_xor(sj[jf], 32);
                }
                float v = (l4 == 0) ? sj[0] : (l4 == 1) ? sj[1]
                        : (l4 == 2) ? sj[2] : sj[3];
                atomicAdd(ev + (size_t)sid * 64 + l, v);
                if (!m) break;
                start = end;
                sid   = __builtin_amdgcn_readlane(s_l, start);
                m &= (m - 1);
            }
        }
    }
}

// ---------------- K2: rho1 + o1 + phi2 (5 fused 64x64 layers) + event-sum ----------------
// one wave per 64 events, 313 blocks -> fills more CUs
__global__ __launch_bounds__(64) void k2_events(
    const float* __restrict__ ev,
    const float* __restrict__ W0, const float* __restrict__ B0,
    const float* __restrict__ W1, const float* __restrict__ B1,
    const float* __restrict__ W2, const float* __restrict__ B2,
    const float* __restrict__ W3, const float* __restrict__ B3,
    const float* __restrict__ W4, const float* __restrict__ B4,
    float* __restrict__ s2) {
    __shared__ __align__(16) __bf16 xt[64 * 72];   // [e][k], stride 72
    const int l   = threadIdx.x;
    const int l15 = l & 15;
    const int l4  = l >> 4;
    const int ebase = blockIdx.x * 64;

    const float* Ws[5] = {W0, W1, W2, W3, W4};
    const float* Bs[5] = {B0, B1, B2, B3, B4};

    // A fragments from ev (layer-0 input), masked for e >= NE
    bf16x8 A[4][2];
#pragma unroll
    for (int pf = 0; pf < 4; pf++) {
        const int e = ebase + pf * 16 + l15;
#pragma unroll
        for (int kf = 0; kf < 2; kf++) {
            bf16x8 a;
            if (e < NE) {
                const float* p = ev + (size_t)e * 64 + kf * 32 + l4 * 8;
                fvec4 x = *(const fvec4*)p;
                fvec4 y = *(const fvec4*)(p + 4);
#pragma unroll
                for (int e2 = 0; e2 < 4; e2++) {
                    a[e2]     = (__bf16)x[e2];
                    a[e2 + 4] = (__bf16)y[e2];
                }
            } else {
#pragma unroll
                for (int e2 = 0; e2 < 8; e2++) a[e2] = (__bf16)0.f;
            }
            A[pf][kf] = a;
        }
    }

#pragma unroll
    for (int L = 0; L < 5; L++) {
        bf16x8 Bh[2][4], Bl[2][4];
#pragma unroll
        for (int kf = 0; kf < 2; kf++)
#pragma unroll
            for (int jf = 0; jf < 4; jf++)
                load_bsplit(Ws[L] + (jf * 16 + l15) * 64 + kf * 32 + l4 * 8,
                            Bh[kf][jf], Bl[kf][jf]);

        f32x4 acc[4][4];
#pragma unroll
        for (int jf = 0; jf < 4; jf++) {
            const float bj = Bs[L][jf * 16 + l15];
#pragma unroll
            for (int pf = 0; pf < 4; pf++)
#pragma unroll
                for (int r = 0; r < 4; r++) acc[pf][jf][r] = bj;
        }
#pragma unroll
        for (int kf = 0; kf < 2; kf++)
#pragma unroll
            for (int pf = 0; pf < 4; pf++)
#pragma unroll
                for (int jf = 0; jf < 4; jf++)
                    acc[pf][jf] = __builtin_amdgcn_mfma_f32_16x16x32_bf16(
                        A[pf][kf], Bh[kf][jf], acc[pf][jf], 0, 0, 0);
#pragma unroll
        for (int kf = 0; kf < 2; kf++)
#pragma unroll
            for (int pf = 0; pf < 4; pf++)
#pragma unroll
                for (int jf = 0; jf < 4; jf++)
                    acc[pf][jf] = __builtin_amdgcn_mfma_f32_16x16x32_bf16(
                        A[pf][kf], Bl[kf][jf], acc[pf][jf], 0, 0, 0);

        if (L < 4) {
            // relu -> LDS [e][j] bf16, then reload as next layer's A-frags
#pragma unroll
            for (int pf = 0; pf < 4; pf++)
#pragma unroll
                for (int jf = 0; jf < 4; jf++) {
                    const int j = jf * 16 + l15;
#pragma unroll
                    for (int r = 0; r < 4; r++)
                        xt[(pf * 16 + l4 * 4 + r) * 72 + j] =
                            (__bf16)fmaxf(acc[pf][jf][r], 0.f);
                }
#pragma unroll
            for (int pf = 0; pf < 4; pf++)
#pragma unroll
                for (int kf = 0; kf < 2; kf++)
                    A[pf][kf] = *(const bf16x8*)(xt + (pf * 16 + l15) * 72 +
                                                 kf * 32 + l4 * 8);
        } else {
            // final phi2 layer: relu, masked sum over events, atomic into s2
            float sj[4];
#pragma unroll
            for (int jf = 0; jf < 4; jf++) {
                float s = 0.f;
#pragma unroll
                for (int pf = 0; pf < 4; pf++)
#pragma unroll
                    for (int r = 0; r < 4; r++) {
                        const int e = ebase + pf * 16 + l4 * 4 + r;
                        float v = fmaxf(acc[pf][jf][r], 0.f);
                        s += (e < NE) ? v : 0.f;
                    }
                s += __shfl_xor(s, 16);
                s += __shfl_xor(s, 32);
                sj[jf] = s;
            }
            float v = (l4 == 0) ? sj[0] : (l4 == 1) ? sj[1]
                    : (l4 == 2) ? sj[2] : sj[3];
            atomicAdd(s2 + l, v);
        }
    }
}

// ---------------- K3: rho2 + output + log_softmax (tiny) ----------------
__global__ __launch_bounds__(64) void k3_final(
    const float* __restrict__ s2,
    const float* __restrict__ W0, const float* __restrict__ B0,
    const float* __restrict__ W1, const float* __restrict__ B1,
    const float* __restrict__ W2, const float* __restrict__ B2,
    float* __restrict__ out) {
    __shared__ __align__(16) float xb[64];
    __shared__ __align__(16) float yb[64];
    __shared__ float ob[10];
    const int l = threadIdx.x;

    xb[l] = s2[l];
    __syncthreads();

    float a = B0[l];
#pragma unroll
    for (int k = 0; k < 16; k++) {
        fvec4 wv = *(const fvec4*)(W0 + l * 64 + k * 4);
        fvec4 xv = *(const fvec4*)(xb + k * 4);
        a += wv[0] * xv[0] + wv[1] * xv[1] + wv[2] * xv[2] + wv[3] * xv[3];
    }
    yb[l] = fmaxf(a, 0.f);
    __syncthreads();

    float b_ = B1[l];
#pragma unroll
    for (int k = 0; k < 16; k++) {
        fvec4 wv = *(const fvec4*)(W1 + l * 64 + k * 4);
        fvec4 xv = *(const fvec4*)(yb + k * 4);
        b_ += wv[0] * xv[0] + wv[1] * xv[1] + wv[2] * xv[2] + wv[3] * xv[3];
    }
    __syncthreads();
    xb[l] = fmaxf(b_, 0.f);
    __syncthreads();

    if (l < 10) {
        float o = B2[l];
#pragma unroll
        for (int k = 0; k < 16; k++) {
            fvec4 wv = *(const fvec4*)(W2 + l * 64 + k * 4);
            fvec4 xv = *(const fvec4*)(xb + k * 4);
            o += wv[0] * xv[0] + wv[1] * xv[1] + wv[2] * xv[2] + wv[3] * xv[3];
        }
        ob[l] = o;
    }
    __syncthreads();
    if (l == 0) {
        float m = ob[0];
#pragma unroll
        for (int i = 1; i < 10; i++) m = fmaxf(m, ob[i]);
        float sum = 0.f;
#pragma unroll
        for (int i = 0; i < 10; i++) sum = sum + expf(ob[i] - m);
        float ls = logf(sum);
#pragma unroll
        for (int i = 0; i < 10; i++) out[i] = ob[i] - m - ls;
    }
}

extern "C" void kernel_launch(void* const* d_in, const int* in_sizes, int n_in,
                              void* d_out, int out_size, void* d_ws, size_t ws_size,
                              hipStream_t stream) {
    const float* values = (const float*)d_in[0];
    const int*   seg    = (const int*)d_in[1];
    const float* p1w0 = (const float*)d_in[2],  *p1b0 = (const float*)d_in[3];
    const float* p1w1 = (const float*)d_in[4],  *p1b1 = (const float*)d_in[5];
    const float* r1w0 = (const float*)d_in[6],  *r1b0 = (const float*)d_in[7];
    const float* r1w1 = (const float*)d_in[8],  *r1b1 = (const float*)d_in[9];
    const float* o1w  = (const float*)d_in[10], *o1b  = (const float*)d_in[11];
    const float* p2w0 = (const float*)d_in[12], *p2b0 = (const float*)d_in[13];
    const float* p2w1 = (const float*)d_in[14], *p2b1 = (const float*)d_in[15];
    const float* r2w0 = (const float*)d_in[16], *r2b0 = (const float*)d_in[17];
    const float* r2w1 = (const float*)d_in[18], *r2b1 = (const float*)d_in[19];
    const float* o2w  = (const float*)d_in[20], *o2b  = (const float*)d_in[21];

    float* ev = (float*)d_ws;                       // [NE][64] accumulators
    float* s2 = ev + (size_t)NE * 64;               // [64]

    hipMemsetAsync(d_ws, 0, (size_t)(NE * 64 + 64) * sizeof(float), stream);

    hipLaunchKernelGGL(k1_phi1, dim3(2048), dim3(256), 0, stream,
                       values, seg, p1w0, p1b0, p1w1, p1b1, ev);
    hipLaunchKernelGGL(k2_events, dim3((NE + 63) / 64), dim3(64), 0, stream,
                       ev, r1w0, r1b0, r1w1, r1b1, o1w, o1b,
                       p2w0, p2b0, p2w1, p2b1, s2);
    hipLaunchKernelGGL(k3_final, dim3(1), dim3(64), 0, stream,
                       s2, r2w0, r2b0, r2w1, r2b1, o2w, o2b, (float*)d_out);
}

// Round 3
// 83.894 us; speedup vs baseline: 1.4795x; 1.4795x over previous
//
#include <hip/hip_runtime.h>

#define NT 2000000
#define NE 20000
#define NTILES (NT / 64)   // 31250, exact

using bf16x8 = __attribute__((ext_vector_type(8))) __bf16;
using bf16x4 = __attribute__((ext_vector_type(4))) __bf16;
using f32x4  = __attribute__((ext_vector_type(4))) float;
using fvec4  = __attribute__((ext_vector_type(4))) float;

// hi/lo bf16 split of 8 consecutive f32 (for k2 precision)
__device__ __forceinline__ void load_bsplit(const float* __restrict__ p,
                                            bf16x8& hi, bf16x8& lo) {
    fvec4 a = *(const fvec4*)p;
    fvec4 b = *(const fvec4*)(p + 4);
#pragma unroll
    for (int e = 0; e < 4; e++) {
        float v  = a[e];
        __bf16 h = (__bf16)v;
        hi[e]    = h;
        lo[e]    = (__bf16)(v - (float)h);
        float v2  = b[e];
        __bf16 h2 = (__bf16)v2;
        hi[e + 4] = h2;
        lo[e + 4] = (__bf16)(v2 - (float)h2);
    }
}

// plain bf16 load of 8 consecutive f32
__device__ __forceinline__ bf16x8 load_bf8(const float* __restrict__ p) {
    fvec4 a = *(const fvec4*)p;
    fvec4 b = *(const fvec4*)(p + 4);
    bf16x8 r;
#pragma unroll
    for (int e = 0; e < 4; e++) {
        r[e]     = (__bf16)a[e];
        r[e + 4] = (__bf16)b[e];
    }
    return r;
}

// ---------------- K1: fused phi1 (2 layers) + jagged segment-sum ----------------
// No LDS. Reduce straight from MFMA C-layout; ballot-driven run handling.
// launch_bounds(256,2): 104-130 VGPR + AGPR accumulators, NO spills (the
// (256,3) variant forced 84 VGPR -> 240 MB of scratch traffic, round 2).
__global__ __launch_bounds__(256, 2) void k1_phi1(
    const float* __restrict__ values, const int* __restrict__ seg,
    const float* __restrict__ w0, const float* __restrict__ b0,
    const float* __restrict__ w1, const float* __restrict__ b1,
    float* __restrict__ ev) {
    const int tid = threadIdx.x;
    const int w   = tid >> 6;
    const int l   = tid & 63;
    const int l15 = l & 15;
    const int l4  = l >> 4;

    // B fragments for W1 (bf16): lane holds col j=16jf+l15, k = 32kf+8*l4+e
    bf16x8 Bh[2][4];
#pragma unroll
    for (int kf = 0; kf < 2; kf++)
#pragma unroll
        for (int jf = 0; jf < 4; jf++)
            Bh[kf][jf] = load_bf8(w1 + (jf * 16 + l15) * 64 + kf * 32 + l4 * 8);

    // layer-1 weights (f32-exact) for this lane's 8 k's per kf
    float w0q[2][8], b0q[2][8];
#pragma unroll
    for (int kf = 0; kf < 2; kf++) {
        const int kb = kf * 32 + l4 * 8;
        fvec4 wa = *(const fvec4*)(w0 + kb);
        fvec4 wb = *(const fvec4*)(w0 + kb + 4);
        fvec4 ba = *(const fvec4*)(b0 + kb);
        fvec4 bb = *(const fvec4*)(b0 + kb + 4);
#pragma unroll
        for (int e = 0; e < 4; e++) {
            w0q[kf][e]     = wa[e];
            w0q[kf][e + 4] = wb[e];
            b0q[kf][e]     = ba[e];
            b0q[kf][e + 4] = bb[e];
        }
    }
    float biasj[4];
#pragma unroll
    for (int jf = 0; jf < 4; jf++) biasj[jf] = b1[jf * 16 + l15];

    for (int tile = blockIdx.x * 4 + w; tile < NTILES; tile += gridDim.x * 4) {
        const int base = tile * 64;
        const int s_l  = seg[base + l];                 // lane l: seg of particle l
        const int prev = __shfl_up(s_l, 1);
        const unsigned long long bmask = __ballot((l > 0) && (s_l != prev));

        float vp[4];
#pragma unroll
        for (int pf = 0; pf < 4; pf++) vp[pf] = values[base + pf * 16 + l15];

        f32x4 acc[4][4];
#pragma unroll
        for (int pf = 0; pf < 4; pf++)
#pragma unroll
            for (int jf = 0; jf < 4; jf++)
#pragma unroll
                for (int r = 0; r < 4; r++) acc[pf][jf][r] = biasj[jf];

#pragma unroll
        for (int kf = 0; kf < 2; kf++) {
            // h1 = relu(v*w0+b0) built directly in A-fragment layout (f32 math)
            bf16x8 A[4];
#pragma unroll
            for (int pf = 0; pf < 4; pf++) {
#pragma unroll
                for (int e = 0; e < 8; e++) {
                    float h = fmaxf(fmaf(vp[pf], w0q[kf][e], b0q[kf][e]), 0.f);
                    A[pf][e] = (__bf16)h;
                }
            }
#pragma unroll
            for (int pf = 0; pf < 4; pf++)
#pragma unroll
                for (int jf = 0; jf < 4; jf++)
                    acc[pf][jf] = __builtin_amdgcn_mfma_f32_16x16x32_bf16(
                        A[pf], Bh[kf][jf], acc[pf][jf], 0, 0, 0);
        }

        // relu in-register (h2), f32 precision kept for the reduce
#pragma unroll
        for (int pf = 0; pf < 4; pf++)
#pragma unroll
            for (int jf = 0; jf < 4; jf++)
#pragma unroll
                for (int r = 0; r < 4; r++)
                    acc[pf][jf][r] = fmaxf(acc[pf][jf][r], 0.f);

        if (bmask == 0ULL) {
            // uniform tile: full column sums, one atomic per lane (feature j==l)
            const int sid = __builtin_amdgcn_readlane(s_l, 0);
            float sj[4];
#pragma unroll
            for (int jf = 0; jf < 4; jf++) {
                f32x4 t = (acc[0][jf] + acc[1][jf]) + (acc[2][jf] + acc[3][jf]);
                float h = (t[0] + t[1]) + (t[2] + t[3]);
                h += __shfl_xor(h, 16);
                h += __shfl_xor(h, 32);
                sj[jf] = h;
            }
            float v = (l4 == 0) ? sj[0] : (l4 == 1) ? sj[1]
                    : (l4 == 2) ? sj[2] : sj[3];
            atomicAdd(ev + (size_t)sid * 64 + l, v);
        } else {
            // run loop: boundaries are wave-uniform scalars from the ballot mask
            unsigned long long m = bmask;
            int start = 0;
            int sid   = __builtin_amdgcn_readlane(s_l, 0);
            while (true) {
                const int end = m ? (int)__builtin_ctzll(m) : 64;
                float sj[4] = {0.f, 0.f, 0.f, 0.f};
#pragma unroll
                for (int pf = 0; pf < 4; pf++)
#pragma unroll
                    for (int r = 0; r < 4; r++) {
                        const int p  = pf * 16 + l4 * 4 + r;
                        const float pm = (p >= start && p < end) ? 1.f : 0.f;
#pragma unroll
                        for (int jf = 0; jf < 4; jf++)
                            sj[jf] = fmaf(acc[pf][jf][r], pm, sj[jf]);
                    }
#pragma unroll
                for (int jf = 0; jf < 4; jf++) {
                    sj[jf] += __shfl_xor(sj[jf], 16);
                    sj[jf] += __shfl_xor(sj[jf], 32);
                }
                float v = (l4 == 0) ? sj[0] : (l4 == 1) ? sj[1]
                        : (l4 == 2) ? sj[2] : sj[3];
                atomicAdd(ev + (size_t)sid * 64 + l, v);
                if (!m) break;
                start = end;
                sid   = __builtin_amdgcn_readlane(s_l, start);
                m &= (m - 1);
            }
        }
    }
}

// ---------------- K2: rho1 + o1 + phi2 (5 fused 64x64 layers) + event-sum ----------------
// one wave per 64 events, 313 blocks -> fills more CUs
__global__ __launch_bounds__(64) void k2_events(
    const float* __restrict__ ev,
    const float* __restrict__ W0, const float* __restrict__ B0,
    const float* __restrict__ W1, const float* __restrict__ B1,
    const float* __restrict__ W2, const float* __restrict__ B2,
    const float* __restrict__ W3, const float* __restrict__ B3,
    const float* __restrict__ W4, const float* __restrict__ B4,
    float* __restrict__ s2) {
    __shared__ __align__(16) __bf16 xt[64 * 72];   // [e][k], stride 72
    const int l   = threadIdx.x;
    const int l15 = l & 15;
    const int l4  = l >> 4;
    const int ebase = blockIdx.x * 64;

    const float* Ws[5] = {W0, W1, W2, W3, W4};
    const float* Bs[5] = {B0, B1, B2, B3, B4};

    // A fragments from ev (layer-0 input), masked for e >= NE
    bf16x8 A[4][2];
#pragma unroll
    for (int pf = 0; pf < 4; pf++) {
        const int e = ebase + pf * 16 + l15;
#pragma unroll
        for (int kf = 0; kf < 2; kf++) {
            bf16x8 a;
            if (e < NE) {
                const float* p = ev + (size_t)e * 64 + kf * 32 + l4 * 8;
                fvec4 x = *(const fvec4*)p;
                fvec4 y = *(const fvec4*)(p + 4);
#pragma unroll
                for (int e2 = 0; e2 < 4; e2++) {
                    a[e2]     = (__bf16)x[e2];
                    a[e2 + 4] = (__bf16)y[e2];
                }
            } else {
#pragma unroll
                for (int e2 = 0; e2 < 8; e2++) a[e2] = (__bf16)0.f;
            }
            A[pf][kf] = a;
        }
    }

#pragma unroll
    for (int L = 0; L < 5; L++) {
        bf16x8 Bh[2][4], Bl[2][4];
#pragma unroll
        for (int kf = 0; kf < 2; kf++)
#pragma unroll
            for (int jf = 0; jf < 4; jf++)
                load_bsplit(Ws[L] + (jf * 16 + l15) * 64 + kf * 32 + l4 * 8,
                            Bh[kf][jf], Bl[kf][jf]);

        f32x4 acc[4][4];
#pragma unroll
        for (int jf = 0; jf < 4; jf++) {
            const float bj = Bs[L][jf * 16 + l15];
#pragma unroll
            for (int pf = 0; pf < 4; pf++)
#pragma unroll
                for (int r = 0; r < 4; r++) acc[pf][jf][r] = bj;
        }
#pragma unroll
        for (int kf = 0; kf < 2; kf++)
#pragma unroll
            for (int pf = 0; pf < 4; pf++)
#pragma unroll
                for (int jf = 0; jf < 4; jf++)
                    acc[pf][jf] = __builtin_amdgcn_mfma_f32_16x16x32_bf16(
                        A[pf][kf], Bh[kf][jf], acc[pf][jf], 0, 0, 0);
#pragma unroll
        for (int kf = 0; kf < 2; kf++)
#pragma unroll
            for (int pf = 0; pf < 4; pf++)
#pragma unroll
                for (int jf = 0; jf < 4; jf++)
                    acc[pf][jf] = __builtin_amdgcn_mfma_f32_16x16x32_bf16(
                        A[pf][kf], Bl[kf][jf], acc[pf][jf], 0, 0, 0);

        if (L < 4) {
            // relu -> LDS [e][j] bf16, then reload as next layer's A-frags
#pragma unroll
            for (int pf = 0; pf < 4; pf++)
#pragma unroll
                for (int jf = 0; jf < 4; jf++) {
                    const int j = jf * 16 + l15;
#pragma unroll
                    for (int r = 0; r < 4; r++)
                        xt[(pf * 16 + l4 * 4 + r) * 72 + j] =
                            (__bf16)fmaxf(acc[pf][jf][r], 0.f);
                }
#pragma unroll
            for (int pf = 0; pf < 4; pf++)
#pragma unroll
                for (int kf = 0; kf < 2; kf++)
                    A[pf][kf] = *(const bf16x8*)(xt + (pf * 16 + l15) * 72 +
                                                 kf * 32 + l4 * 8);
        } else {
            // final phi2 layer: relu, masked sum over events, atomic into s2
            float sj[4];
#pragma unroll
            for (int jf = 0; jf < 4; jf++) {
                float s = 0.f;
#pragma unroll
                for (int pf = 0; pf < 4; pf++)
#pragma unroll
                    for (int r = 0; r < 4; r++) {
                        const int e = ebase + pf * 16 + l4 * 4 + r;
                        float v = fmaxf(acc[pf][jf][r], 0.f);
                        s += (e < NE) ? v : 0.f;
                    }
                s += __shfl_xor(s, 16);
                s += __shfl_xor(s, 32);
                sj[jf] = s;
            }
            float v = (l4 == 0) ? sj[0] : (l4 == 1) ? sj[1]
                    : (l4 == 2) ? sj[2] : sj[3];
            atomicAdd(s2 + l, v);
        }
    }
}

// ---------------- K3: rho2 + output + log_softmax (tiny) ----------------
__global__ __launch_bounds__(64) void k3_final(
    const float* __restrict__ s2,
    const float* __restrict__ W0, const float* __restrict__ B0,
    const float* __restrict__ W1, const float* __restrict__ B1,
    const float* __restrict__ W2, const float* __restrict__ B2,
    float* __restrict__ out) {
    __shared__ __align__(16) float xb[64];
    __shared__ __align__(16) float yb[64];
    __shared__ float ob[10];
    const int l = threadIdx.x;

    xb[l] = s2[l];
    __syncthreads();

    float a = B0[l];
#pragma unroll
    for (int k = 0; k < 16; k++) {
        fvec4 wv = *(const fvec4*)(W0 + l * 64 + k * 4);
        fvec4 xv = *(const fvec4*)(xb + k * 4);
        a += wv[0] * xv[0] + wv[1] * xv[1] + wv[2] * xv[2] + wv[3] * xv[3];
    }
    yb[l] = fmaxf(a, 0.f);
    __syncthreads();

    float b_ = B1[l];
#pragma unroll
    for (int k = 0; k < 16; k++) {
        fvec4 wv = *(const fvec4*)(W1 + l * 64 + k * 4);
        fvec4 xv = *(const fvec4*)(yb + k * 4);
        b_ += wv[0] * xv[0] + wv[1] * xv[1] + wv[2] * xv[2] + wv[3] * xv[3];
    }
    __syncthreads();
    xb[l] = fmaxf(b_, 0.f);
    __syncthreads();

    if (l < 10) {
        float o = B2[l];
#pragma unroll
        for (int k = 0; k < 16; k++) {
            fvec4 wv = *(const fvec4*)(W2 + l * 64 + k * 4);
            fvec4 xv = *(const fvec4*)(xb + k * 4);
            o += wv[0] * xv[0] + wv[1] * xv[1] + wv[2] * xv[2] + wv[3] * xv[3];
        }
        ob[l] = o;
    }
    __syncthreads();
    if (l == 0) {
        float m = ob[0];
#pragma unroll
        for (int i = 1; i < 10; i++) m = fmaxf(m, ob[i]);
        float sum = 0.f;
#pragma unroll
        for (int i = 0; i < 10; i++) sum = sum + expf(ob[i] - m);
        float ls = logf(sum);
#pragma unroll
        for (int i = 0; i < 10; i++) out[i] = ob[i] - m - ls;
    }
}

extern "C" void kernel_launch(void* const* d_in, const int* in_sizes, int n_in,
                              void* d_out, int out_size, void* d_ws, size_t ws_size,
                              hipStream_t stream) {
    const float* values = (const float*)d_in[0];
    const int*   seg    = (const int*)d_in[1];
    const float* p1w0 = (const float*)d_in[2],  *p1b0 = (const float*)d_in[3];
    const float* p1w1 = (const float*)d_in[4],  *p1b1 = (const float*)d_in[5];
    const float* r1w0 = (const float*)d_in[6],  *r1b0 = (const float*)d_in[7];
    const float* r1w1 = (const float*)d_in[8],  *r1b1 = (const float*)d_in[9];
    const float* o1w  = (const float*)d_in[10], *o1b  = (const float*)d_in[11];
    const float* p2w0 = (const float*)d_in[12], *p2b0 = (const float*)d_in[13];
    const float* p2w1 = (const float*)d_in[14], *p2b1 = (const float*)d_in[15];
    const float* r2w0 = (const float*)d_in[16], *r2b0 = (const float*)d_in[17];
    const float* r2w1 = (const float*)d_in[18], *r2b1 = (const float*)d_in[19];
    const float* o2w  = (const float*)d_in[20], *o2b  = (const float*)d_in[21];

    float* ev = (float*)d_ws;                       // [NE][64] accumulators
    float* s2 = ev + (size_t)NE * 64;               // [64]

    hipMemsetAsync(d_ws, 0, (size_t)(NE * 64 + 64) * sizeof(float), stream);

    hipLaunchKernelGGL(k1_phi1, dim3(2048), dim3(256), 0, stream,
                       values, seg, p1w0, p1b0, p1w1, p1b1, ev);
    hipLaunchKernelGGL(k2_events, dim3((NE + 63) / 64), dim3(64), 0, stream,
                       ev, r1w0, r1b0, r1w1, r1b1, o1w, o1b,
                       p2w0, p2b0, p2w1, p2b1, s2);
    hipLaunchKernelGGL(k3_final, dim3(1), dim3(64), 0, stream,
                       s2, r2w0, r2b0, r2w1, r2b1, o2w, o2b, (float*)d_out);
}

// Round 4
// 75.002 us; speedup vs baseline: 1.6549x; 1.1186x over previous
//
#include <hip/hip_runtime.h>

#define NT 2000000
#define NE 20000
#define NTILES (NT / 64)   // 31250, exact

using bf16x8 = __attribute__((ext_vector_type(8))) __bf16;
using bf16x4 = __attribute__((ext_vector_type(4))) __bf16;
using f32x4  = __attribute__((ext_vector_type(4))) float;
using f32x2  = __attribute__((ext_vector_type(2))) float;
using fvec4  = __attribute__((ext_vector_type(4))) float;

// hi/lo bf16 split of 8 consecutive f32 (for k2 precision)
__device__ __forceinline__ void load_bsplit(const float* __restrict__ p,
                                            bf16x8& hi, bf16x8& lo) {
    fvec4 a = *(const fvec4*)p;
    fvec4 b = *(const fvec4*)(p + 4);
#pragma unroll
    for (int e = 0; e < 4; e++) {
        float v  = a[e];
        __bf16 h = (__bf16)v;
        hi[e]    = h;
        lo[e]    = (__bf16)(v - (float)h);
        float v2  = b[e];
        __bf16 h2 = (__bf16)v2;
        hi[e + 4] = h2;
        lo[e + 4] = (__bf16)(v2 - (float)h2);
    }
}

// plain bf16 load of 8 consecutive f32
__device__ __forceinline__ bf16x8 load_bf8(const float* __restrict__ p) {
    fvec4 a = *(const fvec4*)p;
    fvec4 b = *(const fvec4*)(p + 4);
    bf16x8 r;
#pragma unroll
    for (int e = 0; e < 4; e++) {
        r[e]     = (__bf16)a[e];
        r[e + 4] = (__bf16)b[e];
    }
    return r;
}

// ---------------- K1: fused phi1 (2 layers) + jagged segment-sum ----------------
// Half-tile (32-row) accumulators: acc[2][4] = 32 regs -> ~122 unified VGPR,
// fits (256,3) = 12 waves/CU without spilling. (History: full-tile acc at
// (256,3) spilled 240 MB scratch (r2); (256,2) was latency-bound at 18% occ (r3).)
__global__ __launch_bounds__(256, 3) void k1_phi1(
    const float* __restrict__ values, const int* __restrict__ seg,
    const float* __restrict__ w0, const float* __restrict__ b0,
    const float* __restrict__ w1, const float* __restrict__ b1,
    float* __restrict__ ev) {
    const int tid = threadIdx.x;
    const int w   = tid >> 6;
    const int l   = tid & 63;
    const int l15 = l & 15;
    const int l4  = l >> 4;

    // B fragments for W1 (bf16): lane holds col j=16jf+l15, k = 32kf+8*l4+e
    bf16x8 Bh[2][4];
#pragma unroll
    for (int kf = 0; kf < 2; kf++)
#pragma unroll
        for (int jf = 0; jf < 4; jf++)
            Bh[kf][jf] = load_bf8(w1 + (jf * 16 + l15) * 64 + kf * 32 + l4 * 8);

    // layer-1 weights (f32) as f32x2 pairs -> v_pk_fma_f32 in the A-build
    f32x2 w0p[2][4], b0p[2][4];
#pragma unroll
    for (int kf = 0; kf < 2; kf++) {
        const int kb = kf * 32 + l4 * 8;
#pragma unroll
        for (int e2 = 0; e2 < 4; e2++) {
            w0p[kf][e2] = *(const f32x2*)(w0 + kb + e2 * 2);
            b0p[kf][e2] = *(const f32x2*)(b0 + kb + e2 * 2);
        }
    }
    float biasj[4];
#pragma unroll
    for (int jf = 0; jf < 4; jf++) biasj[jf] = b1[jf * 16 + l15];

    for (int tile = blockIdx.x * 4 + w; tile < NTILES; tile += gridDim.x * 4) {
        const int base = tile * 64;
        const int s_l  = seg[base + l];                 // lane l: seg of particle l
        const int prev = __shfl_up(s_l, 1);
        const unsigned long long bmask = __ballot((l > 0) && (s_l != prev));

        float vp[4];
#pragma unroll
        for (int pf = 0; pf < 4; pf++) vp[pf] = values[base + pf * 16 + l15];

#pragma unroll
        for (int q = 0; q < 2; q++) {                   // half-tile: rows [32q,32q+32)
            f32x4 acc[2][4];
#pragma unroll
            for (int i = 0; i < 2; i++)
#pragma unroll
                for (int jf = 0; jf < 4; jf++)
#pragma unroll
                    for (int r = 0; r < 4; r++) acc[i][jf][r] = biasj[jf];

#pragma unroll
            for (int kf = 0; kf < 2; kf++) {
                bf16x8 A[2];
#pragma unroll
                for (int i = 0; i < 2; i++) {           // pf = 2q+i
                    const float vq = vp[2 * q + i];
                    const f32x2 vv = {vq, vq};
#pragma unroll
                    for (int e2 = 0; e2 < 4; e2++) {
                        f32x2 h = w0p[kf][e2] * vv + b0p[kf][e2];   // v_pk_fma_f32
                        A[i][2 * e2]     = (__bf16)fmaxf(h[0], 0.f);
                        A[i][2 * e2 + 1] = (__bf16)fmaxf(h[1], 0.f);
                    }
                }
#pragma unroll
                for (int i = 0; i < 2; i++)
#pragma unroll
                    for (int jf = 0; jf < 4; jf++)
                        acc[i][jf] = __builtin_amdgcn_mfma_f32_16x16x32_bf16(
                            A[i], Bh[kf][jf], acc[i][jf], 0, 0, 0);
            }

            // relu h2 in-register
#pragma unroll
            for (int i = 0; i < 2; i++)
#pragma unroll
                for (int jf = 0; jf < 4; jf++)
#pragma unroll
                    for (int r = 0; r < 4; r++)
                        acc[i][jf][r] = fmaxf(acc[i][jf][r], 0.f);

            // boundary mask restricted to this half; bit0 (= half start) cleared
            const unsigned int mq =
                (unsigned int)(bmask >> (q * 32)) & 0xFFFFFFFEu;

            if (mq == 0u) {
                // uniform half: column sums, one atomic per lane (feature j==l)
                const int sid = __builtin_amdgcn_readlane(s_l, q * 32);
                float sj[4];
#pragma unroll
                for (int jf = 0; jf < 4; jf++) {
                    f32x4 t = acc[0][jf] + acc[1][jf];
                    float h = (t[0] + t[1]) + (t[2] + t[3]);
                    h += __shfl_xor(h, 16);
                    h += __shfl_xor(h, 32);
                    sj[jf] = h;
                }
                float v = (l4 == 0) ? sj[0] : (l4 == 1) ? sj[1]
                        : (l4 == 2) ? sj[2] : sj[3];
                atomicAdd(ev + (size_t)sid * 64 + l, v);
            } else {
                // run loop over boundaries within the half (wave-uniform scalars)
                unsigned int m = mq;
                int start = 0;
                int sid   = __builtin_amdgcn_readlane(s_l, q * 32);
                while (true) {
                    const int end = m ? (int)__builtin_ctz(m) : 32;
                    float sj[4] = {0.f, 0.f, 0.f, 0.f};
#pragma unroll
                    for (int i = 0; i < 2; i++)
#pragma unroll
                        for (int r = 0; r < 4; r++) {
                            const int rel = i * 16 + l4 * 4 + r;
                            const float pm = (rel >= start && rel < end) ? 1.f : 0.f;
#pragma unroll
                            for (int jf = 0; jf < 4; jf++)
                                sj[jf] = fmaf(acc[i][jf][r], pm, sj[jf]);
                        }
#pragma unroll
                    for (int jf = 0; jf < 4; jf++) {
                        sj[jf] += __shfl_xor(sj[jf], 16);
                        sj[jf] += __shfl_xor(sj[jf], 32);
                    }
                    float v = (l4 == 0) ? sj[0] : (l4 == 1) ? sj[1]
                            : (l4 == 2) ? sj[2] : sj[3];
                    atomicAdd(ev + (size_t)sid * 64 + l, v);
                    if (!m) break;
                    start = end;
                    sid   = __builtin_amdgcn_readlane(s_l, q * 32 + start);
                    m &= (m - 1);
                }
            }
        }
    }
}

// ---------------- K2: rho1 + o1 + phi2 (5 fused 64x64 layers) + event-sum ----------------
// one wave per 64 events, 313 blocks -> fills more CUs
__global__ __launch_bounds__(64) void k2_events(
    const float* __restrict__ ev,
    const float* __restrict__ W0, const float* __restrict__ B0,
    const float* __restrict__ W1, const float* __restrict__ B1,
    const float* __restrict__ W2, const float* __restrict__ B2,
    const float* __restrict__ W3, const float* __restrict__ B3,
    const float* __restrict__ W4, const float* __restrict__ B4,
    float* __restrict__ s2) {
    __shared__ __align__(16) __bf16 xt[64 * 72];   // [e][k], stride 72
    const int l   = threadIdx.x;
    const int l15 = l & 15;
    const int l4  = l >> 4;
    const int ebase = blockIdx.x * 64;

    const float* Ws[5] = {W0, W1, W2, W3, W4};
    const float* Bs[5] = {B0, B1, B2, B3, B4};

    // A fragments from ev (layer-0 input), masked for e >= NE
    bf16x8 A[4][2];
#pragma unroll
    for (int pf = 0; pf < 4; pf++) {
        const int e = ebase + pf * 16 + l15;
#pragma unroll
        for (int kf = 0; kf < 2; kf++) {
            bf16x8 a;
            if (e < NE) {
                const float* p = ev + (size_t)e * 64 + kf * 32 + l4 * 8;
                fvec4 x = *(const fvec4*)p;
                fvec4 y = *(const fvec4*)(p + 4);
#pragma unroll
                for (int e2 = 0; e2 < 4; e2++) {
                    a[e2]     = (__bf16)x[e2];
                    a[e2 + 4] = (__bf16)y[e2];
                }
            } else {
#pragma unroll
                for (int e2 = 0; e2 < 8; e2++) a[e2] = (__bf16)0.f;
            }
            A[pf][kf] = a;
        }
    }

#pragma unroll
    for (int L = 0; L < 5; L++) {
        bf16x8 Bh[2][4], Bl[2][4];
#pragma unroll
        for (int kf = 0; kf < 2; kf++)
#pragma unroll
            for (int jf = 0; jf < 4; jf++)
                load_bsplit(Ws[L] + (jf * 16 + l15) * 64 + kf * 32 + l4 * 8,
                            Bh[kf][jf], Bl[kf][jf]);

        f32x4 acc[4][4];
#pragma unroll
        for (int jf = 0; jf < 4; jf++) {
            const float bj = Bs[L][jf * 16 + l15];
#pragma unroll
            for (int pf = 0; pf < 4; pf++)
#pragma unroll
                for (int r = 0; r < 4; r++) acc[pf][jf][r] = bj;
        }
#pragma unroll
        for (int kf = 0; kf < 2; kf++)
#pragma unroll
            for (int pf = 0; pf < 4; pf++)
#pragma unroll
                for (int jf = 0; jf < 4; jf++)
                    acc[pf][jf] = __builtin_amdgcn_mfma_f32_16x16x32_bf16(
                        A[pf][kf], Bh[kf][jf], acc[pf][jf], 0, 0, 0);
#pragma unroll
        for (int kf = 0; kf < 2; kf++)
#pragma unroll
            for (int pf = 0; pf < 4; pf++)
#pragma unroll
                for (int jf = 0; jf < 4; jf++)
                    acc[pf][jf] = __builtin_amdgcn_mfma_f32_16x16x32_bf16(
                        A[pf][kf], Bl[kf][jf], acc[pf][jf], 0, 0, 0);

        if (L < 4) {
            // relu -> LDS [e][j] bf16, then reload as next layer's A-frags
#pragma unroll
            for (int pf = 0; pf < 4; pf++)
#pragma unroll
                for (int jf = 0; jf < 4; jf++) {
                    const int j = jf * 16 + l15;
#pragma unroll
                    for (int r = 0; r < 4; r++)
                        xt[(pf * 16 + l4 * 4 + r) * 72 + j] =
                            (__bf16)fmaxf(acc[pf][jf][r], 0.f);
                }
#pragma unroll
            for (int pf = 0; pf < 4; pf++)
#pragma unroll
                for (int kf = 0; kf < 2; kf++)
                    A[pf][kf] = *(const bf16x8*)(xt + (pf * 16 + l15) * 72 +
                                                 kf * 32 + l4 * 8);
        } else {
            // final phi2 layer: relu, masked sum over events, atomic into s2
            float sj[4];
#pragma unroll
            for (int jf = 0; jf < 4; jf++) {
                float s = 0.f;
#pragma unroll
                for (int pf = 0; pf < 4; pf++)
#pragma unroll
                    for (int r = 0; r < 4; r++) {
                        const int e = ebase + pf * 16 + l4 * 4 + r;
                        float v = fmaxf(acc[pf][jf][r], 0.f);
                        s += (e < NE) ? v : 0.f;
                    }
                s += __shfl_xor(s, 16);
                s += __shfl_xor(s, 32);
                sj[jf] = s;
            }
            float v = (l4 == 0) ? sj[0] : (l4 == 1) ? sj[1]
                    : (l4 == 2) ? sj[2] : sj[3];
            atomicAdd(s2 + l, v);
        }
    }
}

// ---------------- K3: rho2 + output + log_softmax (tiny) ----------------
__global__ __launch_bounds__(64) void k3_final(
    const float* __restrict__ s2,
    const float* __restrict__ W0, const float* __restrict__ B0,
    const float* __restrict__ W1, const float* __restrict__ B1,
    const float* __restrict__ W2, const float* __restrict__ B2,
    float* __restrict__ out) {
    __shared__ __align__(16) float xb[64];
    __shared__ __align__(16) float yb[64];
    __shared__ float ob[10];
    const int l = threadIdx.x;

    xb[l] = s2[l];
    __syncthreads();

    float a = B0[l];
#pragma unroll
    for (int k = 0; k < 16; k++) {
        fvec4 wv = *(const fvec4*)(W0 + l * 64 + k * 4);
        fvec4 xv = *(const fvec4*)(xb + k * 4);
        a += wv[0] * xv[0] + wv[1] * xv[1] + wv[2] * xv[2] + wv[3] * xv[3];
    }
    yb[l] = fmaxf(a, 0.f);
    __syncthreads();

    float b_ = B1[l];
#pragma unroll
    for (int k = 0; k < 16; k++) {
        fvec4 wv = *(const fvec4*)(W1 + l * 64 + k * 4);
        fvec4 xv = *(const fvec4*)(yb + k * 4);
        b_ += wv[0] * xv[0] + wv[1] * xv[1] + wv[2] * xv[2] + wv[3] * xv[3];
    }
    __syncthreads();
    xb[l] = fmaxf(b_, 0.f);
    __syncthreads();

    if (l < 10) {
        float o = B2[l];
#pragma unroll
        for (int k = 0; k < 16; k++) {
            fvec4 wv = *(const fvec4*)(W2 + l * 64 + k * 4);
            fvec4 xv = *(const fvec4*)(xb + k * 4);
            o += wv[0] * xv[0] + wv[1] * xv[1] + wv[2] * xv[2] + wv[3] * xv[3];
        }
        ob[l] = o;
    }
    __syncthreads();
    if (l == 0) {
        float m = ob[0];
#pragma unroll
        for (int i = 1; i < 10; i++) m = fmaxf(m, ob[i]);
        float sum = 0.f;
#pragma unroll
        for (int i = 0; i < 10; i++) sum = sum + expf(ob[i] - m);
        float ls = logf(sum);
#pragma unroll
        for (int i = 0; i < 10; i++) out[i] = ob[i] - m - ls;
    }
}

extern "C" void kernel_launch(void* const* d_in, const int* in_sizes, int n_in,
                              void* d_out, int out_size, void* d_ws, size_t ws_size,
                              hipStream_t stream) {
    const float* values = (const float*)d_in[0];
    const int*   seg    = (const int*)d_in[1];
    const float* p1w0 = (const float*)d_in[2],  *p1b0 = (const float*)d_in[3];
    const float* p1w1 = (const float*)d_in[4],  *p1b1 = (const float*)d_in[5];
    const float* r1w0 = (const float*)d_in[6],  *r1b0 = (const float*)d_in[7];
    const float* r1w1 = (const float*)d_in[8],  *r1b1 = (const float*)d_in[9];
    const float* o1w  = (const float*)d_in[10], *o1b  = (const float*)d_in[11];
    const float* p2w0 = (const float*)d_in[12], *p2b0 = (const float*)d_in[13];
    const float* p2w1 = (const float*)d_in[14], *p2b1 = (const float*)d_in[15];
    const float* r2w0 = (const float*)d_in[16], *r2b0 = (const float*)d_in[17];
    const float* r2w1 = (const float*)d_in[18], *r2b1 = (const float*)d_in[19];
    const float* o2w  = (const float*)d_in[20], *o2b  = (const float*)d_in[21];

    float* ev = (float*)d_ws;                       // [NE][64] accumulators
    float* s2 = ev + (size_t)NE * 64;               // [64]

    hipMemsetAsync(d_ws, 0, (size_t)(NE * 64 + 64) * sizeof(float), stream);

    hipLaunchKernelGGL(k1_phi1, dim3(2048), dim3(256), 0, stream,
                       values, seg, p1w0, p1b0, p1w1, p1b1, ev);
    hipLaunchKernelGGL(k2_events, dim3((NE + 63) / 64), dim3(64), 0, stream,
                       ev, r1w0, r1b0, r1w1, r1b1, o1w, o1b,
                       p2w0, p2b0, p2w1, p2b1, s2);
    hipLaunchKernelGGL(k3_final, dim3(1), dim3(64), 0, stream,
                       s2, r2w0, r2b0, r2w1, r2b1, o2w, o2b, (float*)d_out);
}